// Round 6
// baseline (507.646 us; speedup 1.0000x reference)
//
#include <hip/hip_runtime.h>
#include <math.h>

#define NN 50000
#define EE 800000
#define AIN 256
#define OH 128

#define NTOT  (2 * NN)        // combined node ids: set0 = [0,NN), set1 = [NN,2NN)
#define NB    391             // buckets of 256 nodes
#define CAP   5120            // per-bucket stage capacity (mean 4092, +16 sigma)
#define MT    391             // row tiles (128 rows each)
#define RPX   49              // ceil(MT/8) row tiles per XCD

// fuse1 grid layout
#define F1_CVTX  12500        // NN*AIN/4 / 256
#define F1_CVTW  640
#define F1_BIN   196          // ceil(2*EE / 8192)
// fuse2 grid layout
#define F2_QKVF  (8 * RPX * 4)   // 1568
// fuse2 LDS plan (bytes):
//   qkvf:     As[128][40] @0 (10240) | Bs[128][40] @10240 (10240)   = 20480
//   sortpass: srec[CAP]u32 @0 (20480) | sloc[CAP]u8 @20480 (5120) |
//             h @25600 | eb @26624 | cur @27648 | red @28672        = 29696
#define F2_SMEM  29696

typedef __attribute__((ext_vector_type(8))) short bf16x8;
typedef __attribute__((ext_vector_type(4))) float f32x4;
typedef __attribute__((ext_vector_type(2))) float f32x2;

static __device__ __forceinline__ unsigned short f2bf(float f) {
    union { float f; unsigned int u; } v; v.f = f;
    return (unsigned short)((v.u + 0x7FFFu + ((v.u >> 16) & 1u)) >> 16);
}
static __device__ __forceinline__ float bflo(unsigned int u) { return __uint_as_float(u << 16); }
static __device__ __forceinline__ float bfhi(unsigned int u) { return __uint_as_float(u & 0xFFFF0000u); }

// ---------------------------------------------------------------------------
// fuse1: three independent preprocessing stages in one dispatch.
//   blocks [0, F1_CVTX)            : x99 f32 -> xb bf16
//   blocks [F1_CVTX, +F1_CVTW)     : weight transpose/cast
//   blocks [F1_CVTX+F1_CVTW, end)  : edge binning (packed rec + loc byte)
// ---------------------------------------------------------------------------
__global__ __launch_bounds__(256) void fuse1_k(
    const float* __restrict__ x99, unsigned short* __restrict__ xb,
    const float* __restrict__ Wq, const float* __restrict__ Wk,
    const float* __restrict__ Wv, const float* __restrict__ Wf,
    const float* __restrict__ Wo, unsigned short* __restrict__ Wt,
    unsigned short* __restrict__ Waot,
    const int* __restrict__ dst0, const int* __restrict__ dst1,
    const int* __restrict__ src0, const int* __restrict__ src1,
    const float* __restrict__ feat0, const float* __restrict__ feat1,
    int* __restrict__ cursor, unsigned int* __restrict__ stage_rec,
    unsigned char* __restrict__ stage_loc)
{
    __shared__ int hcnt[NB], blkbase[NB], lcur[NB];
    const int b = blockIdx.x;
    const int tid = threadIdx.x;

    if (b < F1_CVTX) {
        const int i = b * 256 + tid;
        const float4 v = ((const float4*)x99)[i];
        ushort4 o;
        o.x = f2bf(v.x); o.y = f2bf(v.y); o.z = f2bf(v.z); o.w = f2bf(v.w);
        ((ushort4*)xb)[i] = o;
        return;
    }
    if (b < F1_CVTX + F1_CVTW) {
        const int n = b - F1_CVTX;
        const int k = tid;
        if (n < 512) {
            const float* W = (n < 128) ? Wq : (n < 256) ? Wk : (n < 384) ? Wv : Wf;
            Wt[(size_t)n * 256 + k] = f2bf(W[(size_t)k * OH + (n & 127)]);
        } else {
            if (k < 128) Waot[(size_t)(n - 512) * 128 + k] = f2bf(Wo[(size_t)k * OH + (n - 512)]);
        }
        return;
    }

    // ---- binpass ----
    const int bb = b - (F1_CVTX + F1_CVTW);
    const long base = (long)bb * 8192;

    for (int i = tid; i < NB; i += 256) { hcnt[i] = 0; lcur[i] = 0; }
    __syncthreads();

    for (int i = tid; i < 8192; i += 256) {
        const long e = base + i;
        if (e < 2L * EE) {
            const int nid = (e < EE) ? dst0[e] : NN + dst1[e - EE];
            atomicAdd(&hcnt[nid >> 8], 1);
        }
    }
    __syncthreads();
    for (int i = tid; i < NB; i += 256)
        if (hcnt[i]) blkbase[i] = atomicAdd(&cursor[i], hcnt[i]);
    __syncthreads();

    for (int i = tid; i < 8192; i += 256) {
        const long e = base + i;
        if (e < 2L * EE) {
            const bool a = (e < EE);
            const int ee = a ? (int)e : (int)(e - EE);
            const int nid = a ? dst0[ee] : NN + dst1[ee];
            const int s = a ? src0[ee] : src1[ee];
            const float f = a ? feat0[(size_t)ee * 2] : feat1[(size_t)ee * 2];
            const int bk = nid >> 8;
            const int r = atomicAdd(&lcur[bk], 1);
            const size_t pos = (size_t)bk * CAP + blkbase[bk] + r;
            stage_rec[pos] = ((unsigned int)s << 15) | __float2uint_rn(f * 32767.f);
            stage_loc[pos] = (unsigned char)(nid & 255);
        }
    }
}

// ---------------------------------------------------------------------------
// fuse2: QKV+FFN GEMM blocks + per-bucket sortpass blocks (independent given
// fuse1); sortpass (~391 blocks) hides under the GEMM. bscan is eliminated:
// each sortpass block computes its own prefix over cursor[0..b).
//   blocks [0, F2_QKVF): GEMM, XCD-swizzled (xcd = n&7 owns RPX row tiles;
//     4 y-tiles id-adjacent -> A stripe L2-caches). y=0 q bf16; y=1 K fp8;
//     y=2 V fp8 (K/V INTERLEAVED per 8-dim block: row byte (c>>3)*16+(c&7)
//     for K, +8 for V -> aggregate gathers one dwordx4 per edge); y=3 ffn.
//   blocks [F2_QKVF, +NB): sortpass from LDS, emits packed erec + off/deg.
// ---------------------------------------------------------------------------
__global__ __launch_bounds__(256) void fuse2_k(
    const unsigned short* __restrict__ xb,
    const unsigned short* __restrict__ Wt,
    const float* __restrict__ bq, const float* __restrict__ bk,
    const float* __restrict__ bv, const float* __restrict__ bf,
    unsigned short* __restrict__ qb, unsigned char* __restrict__ kv8,
    unsigned short* __restrict__ ffnb, int M,
    const unsigned int* __restrict__ stage_rec,
    const unsigned char* __restrict__ stage_loc,
    const int* __restrict__ cursor, unsigned int* __restrict__ erec,
    int* __restrict__ off, int* __restrict__ deg)
{
    __shared__ __align__(16) unsigned char smem[F2_SMEM];
    const int b = blockIdx.x;
    const int tid = threadIdx.x;

    if (b < F2_QKVF) {
        // ---- qkvf GEMM ----
        const int xcd  = b & 7;
        const int slot = b >> 3;
        const int rowt = xcd * RPX + (slot >> 2);
        const int y    = slot & 3;
        if (rowt >= MT) return;

        unsigned short (*As)[40] = (unsigned short (*)[40])smem;
        unsigned short (*Bs)[40] = (unsigned short (*)[40])(smem + 10240);

        const int lane = tid & 63;
        const int wave = tid >> 6;
        const int wr = wave >> 1, wc = wave & 1;
        const int quad = lane >> 4, m16 = lane & 15;
        const int row0 = rowt * 128;
        const int col0 = y * 128;

        f32x4 acc[4][4];
        #pragma unroll
        for (int i = 0; i < 4; ++i)
            #pragma unroll
            for (int j = 0; j < 4; ++j) acc[i][j] = 0.f;

        const int lr  = tid >> 1;
        const int lkh = (tid & 1) * 16;

        for (int kt = 0; kt < 256; kt += 32) {
            uint4 a0 = {0,0,0,0}, a1 = {0,0,0,0};
            const int grow = row0 + lr;
            if (grow < M) {
                const uint4* p = (const uint4*)(xb + (size_t)grow * 256 + kt + lkh);
                a0 = p[0]; a1 = p[1];
            }
            *(uint4*)&As[lr][lkh]     = a0;
            *(uint4*)&As[lr][lkh + 8] = a1;
            const uint4* wp = (const uint4*)(Wt + (size_t)(col0 + lr) * 256 + kt + lkh);
            *(uint4*)&Bs[lr][lkh]     = wp[0];
            *(uint4*)&Bs[lr][lkh + 8] = wp[1];
            __syncthreads();
            bf16x8 af[4], bfr[4];
            #pragma unroll
            for (int t = 0; t < 4; ++t) af[t]  = *(const bf16x8*)&As[wr * 64 + t * 16 + m16][quad * 8];
            #pragma unroll
            for (int t = 0; t < 4; ++t) bfr[t] = *(const bf16x8*)&Bs[wc * 64 + t * 16 + m16][quad * 8];
            #pragma unroll
            for (int i = 0; i < 4; ++i)
                #pragma unroll
                for (int j = 0; j < 4; ++j)
                    acc[i][j] = __builtin_amdgcn_mfma_f32_16x16x32_bf16(af[i], bfr[j], acc[i][j], 0, 0, 0);
            __syncthreads();
        }

        const float* bias = (y == 0) ? bq : (y == 1) ? bk : (y == 2) ? bv : bf;

        if (y == 1 || y == 2) {
            const int ocol8 = (y == 2) ? 8 : 0;
            #pragma unroll
            for (int i = 0; i < 4; ++i)
                #pragma unroll
                for (int j = 0; j < 4; ++j) {
                    const int col = wc * 64 + j * 16 + m16;
                    const float bcol = bias[col];
                    const int bpos = ((col >> 3) << 4) + (col & 7) + ocol8;
                    #pragma unroll
                    for (int r = 0; r < 4; ++r) {
                        const int row = row0 + wr * 64 + i * 16 + quad * 4 + r;
                        if (row < M) {
                            const unsigned int pk =
                                (unsigned int)__builtin_amdgcn_cvt_pk_fp8_f32(acc[i][j][r] + bcol, 0.f, 0, 0);
                            kv8[(size_t)row * 256 + bpos] = (unsigned char)(pk & 0xFF);
                        }
                    }
                }
        } else {
            unsigned short* obase = (y == 3) ? ffnb : qb;
            #pragma unroll
            for (int i = 0; i < 4; ++i)
                #pragma unroll
                for (int j = 0; j < 4; ++j) {
                    const int col = wc * 64 + j * 16 + m16;
                    const float bcol = bias[col];
                    #pragma unroll
                    for (int r = 0; r < 4; ++r) {
                        const int row = row0 + wr * 64 + i * 16 + quad * 4 + r;
                        if (row < M) obase[(size_t)row * 128 + col] = f2bf(acc[i][j][r] + bcol);
                    }
                }
        }
        return;
    }

    // ---- sortpass ----
    const int b2 = b - F2_QKVF;
    unsigned int*  srec = (unsigned int*)smem;
    unsigned char* sloc = smem + 20480;
    int* h   = (int*)(smem + 25600);
    int* eb  = (int*)(smem + 26624);
    int* cur = (int*)(smem + 27648);
    int* red = (int*)(smem + 28672);

    const int t = tid;
    const int cntb = min(cursor[b2], CAP);

    h[t] = 0; cur[t] = 0;
    int pre = 0;
    for (int i = t; i < b2; i += 256) pre += cursor[i];
    red[t] = pre;
    __syncthreads();
    for (int s = 128; s > 0; s >>= 1) {
        if (t < s) red[t] += red[t + s];
        __syncthreads();
    }
    const int obase = red[0];

    for (int i = t; i < cntb; i += 256) {
        srec[i] = stage_rec[(size_t)b2 * CAP + i];
        sloc[i] = stage_loc[(size_t)b2 * CAP + i];
    }
    __syncthreads();
    for (int i = t; i < cntb; i += 256) atomicAdd(&h[(int)sloc[i]], 1);
    __syncthreads();
    eb[t] = h[t];
    __syncthreads();
    for (int st = 1; st < 256; st <<= 1) {
        int u = (t >= st) ? eb[t - st] : 0;
        __syncthreads();
        eb[t] += u;
        __syncthreads();
    }
    const int incl = eb[t];
    __syncthreads();
    eb[t] = incl - h[t];          // exclusive
    __syncthreads();

    const int nid = b2 * 256 + t;
    if (nid < NTOT) {
        off[nid] = obase + eb[t];
        deg[nid] = h[t];
    }

    for (int i = t; i < cntb; i += 256) {
        const int loc = (int)sloc[i];
        const int rk = atomicAdd(&cur[loc], 1);
        erec[obase + eb[loc] + rk] = srec[i];
    }
}

// ---------------------------------------------------------------------------
// Aggregation, both edge sets in one dispatch: one wave per combined node id.
// Lane layout: g = lane>>4 is the edge slot (4 edges in flight per wave),
// d16 = lane&15 owns dims [d16*8, d16*8+8). K/V fp8 e4m3, INTERLEAVED per
// 8-dim block ([d16*16, +8) = K, [+8, +16) = V) -> ONE dwordx4 gather per
// edge per lane (was 2 loads + 2 addr chains). Depth-2 batch prefetch hides
// L2 gather latency under the ~2-batch compute window. erec packed
// (src<<15 | feat15): one shuffle delivers src+feat. Head reduce = 2
// shfl_xor; score stays lane-resident for V accumulation; cross-slot
// combine in the epilogue.
// ---------------------------------------------------------------------------
__global__ __launch_bounds__(256) void aggregate_k(
    const unsigned short* __restrict__ qb, const unsigned char* __restrict__ kv8,
    const unsigned int* __restrict__ erec,
    const int* __restrict__ off, const int* __restrict__ deg,
    unsigned short* __restrict__ att)
{
    const int nid = blockIdx.x * 4 + (threadIdx.x >> 6);
    if (nid >= NTOT) return;
    const int n = (nid >= NN) ? nid - NN : nid;
    const int lane = threadIdx.x & 63;
    const int g   = lane >> 4;     // edge slot 0..3
    const int d16 = lane & 15;     // dim-block: dims [d16*8, d16*8+8)
    const int start = off[nid];
    const int count = deg[nid];

    // q: my 8 dims, bf16 -> f32x2 pairs (dims 2i, 2i+1)
    const uint4 qu = *(const uint4*)(qb + (size_t)n * 128 + d16 * 8);
    f32x2 qd0, qd1, qd2, qd3;
    qd0[0] = bflo(qu.x); qd0[1] = bfhi(qu.x);
    qd1[0] = bflo(qu.y); qd1[1] = bfhi(qu.y);
    qd2[0] = bflo(qu.z); qd2[1] = bfhi(qu.z);
    qd3[0] = bflo(qu.w); qd3[1] = bfhi(qu.w);

    f32x2 av0 = 0.f, av1 = 0.f, av2 = 0.f, av3 = 0.f;
    float zp = 0.f;
    const float FSC = 0.088388347648318447f / 32767.0f;  // SCALE * feat-dequant
    const unsigned char* kvl = kv8 + d16 * 16;  // lane-fixed interleaved offset

    for (int base = 0; base < count; base += 64) {
        const int m = min(64, count - base);
        const unsigned int ue = erec[start + base + min(lane, m - 1)];
        // depth-2 prefetch pipeline (dead slots read clamped-valid records)
        unsigned int cuA = (unsigned int)__shfl((int)ue, g);
        uint4 ldA = *(const uint4*)(kvl + (size_t)(cuA >> 15) * 256);
        unsigned int cuB = cuA;
        uint4 ldB = ldA;
        if (4 < m) {
            cuB = (unsigned int)__shfl((int)ue, 4 + g);
            ldB = *(const uint4*)(kvl + (size_t)(cuB >> 15) * 256);
        }
        for (int j0 = 0; j0 < m; j0 += 4) {
            const uint4 kv = ldA;
            const float fs = (float)(cuA & 32767u) * FSC;
            cuA = cuB; ldA = ldB;
            const int j2 = j0 + 8;
            if (j2 < m) {      // uniform branch: issue load 2 batches ahead
                cuB = (unsigned int)__shfl((int)ue, j2 + g);
                ldB = *(const uint4*)(kvl + (size_t)(cuB >> 15) * 256);
            }
            // decode 8 fp8 k dims (4 HW pair-converts), packed dot with q
            const f32x2 k0 = __builtin_amdgcn_cvt_pk_f32_fp8((int)kv.x, false);
            const f32x2 k1 = __builtin_amdgcn_cvt_pk_f32_fp8((int)kv.x, true);
            const f32x2 k2 = __builtin_amdgcn_cvt_pk_f32_fp8((int)kv.y, false);
            const f32x2 k3 = __builtin_amdgcn_cvt_pk_f32_fp8((int)kv.y, true);
            f32x2 p2 = k0 * qd0;
            p2 += k1 * qd1;
            p2 += k2 * qd2;
            p2 += k3 * qd3;
            float p = p2[0] + p2[1];
            // head reduce: 4 lanes (d16 within the same head) = 32 dims
            p += __shfl_xor(p, 1);
            p += __shfl_xor(p, 2);
            float sc = __expf(fminf(5.f, fmaxf(-5.f, p * fs)));
            sc = (j0 + g < m) ? sc : 0.f;
            zp += sc;          // per-lane: my head's z over my slot's edges
            // decode 8 fp8 v dims, packed weighted accumulate
            const f32x2 v0 = __builtin_amdgcn_cvt_pk_f32_fp8((int)kv.z, false);
            const f32x2 v1 = __builtin_amdgcn_cvt_pk_f32_fp8((int)kv.z, true);
            const f32x2 v2 = __builtin_amdgcn_cvt_pk_f32_fp8((int)kv.w, false);
            const f32x2 v3 = __builtin_amdgcn_cvt_pk_f32_fp8((int)kv.w, true);
            f32x2 sc2; sc2[0] = sc; sc2[1] = sc;
            av0 += v0 * sc2;
            av1 += v1 * sc2;
            av2 += v2 * sc2;
            av3 += v3 * sc2;
        }
    }

    // combine the 4 edge slots (lane bits 4,5)
    float z = zp;
    z += __shfl_xor(z, 16);
    z += __shfl_xor(z, 32);
    av0[0] += __shfl_xor(av0[0], 16); av0[0] += __shfl_xor(av0[0], 32);
    av0[1] += __shfl_xor(av0[1], 16); av0[1] += __shfl_xor(av0[1], 32);
    av1[0] += __shfl_xor(av1[0], 16); av1[0] += __shfl_xor(av1[0], 32);
    av1[1] += __shfl_xor(av1[1], 16); av1[1] += __shfl_xor(av1[1], 32);
    av2[0] += __shfl_xor(av2[0], 16); av2[0] += __shfl_xor(av2[0], 32);
    av2[1] += __shfl_xor(av2[1], 16); av2[1] += __shfl_xor(av2[1], 32);
    av3[0] += __shfl_xor(av3[0], 16); av3[0] += __shfl_xor(av3[0], 32);
    av3[1] += __shfl_xor(av3[1], 16); av3[1] += __shfl_xor(av3[1], 32);

    const float inv = 1.f / (z + 1.f);   // per-head z (head = d16>>2)
    // slot g writes dims d16*8 + 2g, 2g+1 = av<g> (static selects, no scratch)
    const f32x2 e01 = (g & 1) ? av1 : av0;
    const f32x2 e23 = (g & 1) ? av3 : av2;
    const f32x2 e   = (g & 2) ? e23 : e01;
    const float ax = e[0] * inv;
    const float ay = e[1] * inv;
    const unsigned int o = ((unsigned int)f2bf(ay) << 16) | (unsigned int)f2bf(ax);
    *(unsigned int*)(att + (size_t)nid * 128 + d16 * 8 + g * 2) = o;
}

// ---------------------------------------------------------------------------
// Output GEMM, XCD-swizzled 1D grid (8 * RPX * 2 blocks): the 2 set-tiles of
// one row tile are id-adjacent on the SAME XCD -> the shared ffnb row panel
// L2-caches (read once instead of twice). LN epilogue in fp32 registers.
// ---------------------------------------------------------------------------
__global__ __launch_bounds__(256) void attn_out_mfma_k(
    const unsigned short* __restrict__ attAll, const unsigned short* __restrict__ Wt,
    const float* __restrict__ bo, const unsigned short* __restrict__ ffnb,
    const float* __restrict__ g, const float* __restrict__ bln,
    float* __restrict__ Yall, int M)
{
    const int nblk = blockIdx.x;
    const int xcd  = nblk & 7;
    const int slot = nblk >> 3;
    const int rowt = xcd * RPX + (slot >> 1);
    const int set  = slot & 1;
    if (rowt >= MT) return;

    __shared__ unsigned short As[128][40];
    __shared__ unsigned short Bs[128][40];
    __shared__ float rsum[2][128], rsq[2][128];
    __shared__ float meanar[128], invar[128];

    const unsigned short* att = attAll + (size_t)set * NN * 128;
    float* Y = Yall + (size_t)set * NN * 128;

    const int tid  = threadIdx.x;
    const int lane = tid & 63;
    const int wave = tid >> 6;
    const int wr = wave >> 1, wc = wave & 1;
    const int quad = lane >> 4, m16 = lane & 15;
    const int row0 = rowt * 128;

    f32x4 acc[4][4];
    #pragma unroll
    for (int i = 0; i < 4; ++i)
        #pragma unroll
        for (int j = 0; j < 4; ++j) acc[i][j] = 0.f;

    const int lr  = tid >> 1;
    const int lkh = (tid & 1) * 16;

    for (int kt = 0; kt < 128; kt += 32) {
        uint4 a0 = {0,0,0,0}, a1 = {0,0,0,0};
        const int grow = row0 + lr;
        if (grow < M) {
            const uint4* p = (const uint4*)(att + (size_t)grow * 128 + kt + lkh);
            a0 = p[0]; a1 = p[1];
        }
        *(uint4*)&As[lr][lkh]     = a0;
        *(uint4*)&As[lr][lkh + 8] = a1;
        const uint4* wp = (const uint4*)(Wt + (size_t)lr * 128 + kt + lkh);
        *(uint4*)&Bs[lr][lkh]     = wp[0];
        *(uint4*)&Bs[lr][lkh + 8] = wp[1];
        __syncthreads();
        bf16x8 af[4], bfr[4];
        #pragma unroll
        for (int t = 0; t < 4; ++t) af[t]  = *(const bf16x8*)&As[wr * 64 + t * 16 + m16][quad * 8];
        #pragma unroll
        for (int t = 0; t < 4; ++t) bfr[t] = *(const bf16x8*)&Bs[wc * 64 + t * 16 + m16][quad * 8];
        #pragma unroll
        for (int i = 0; i < 4; ++i)
            #pragma unroll
            for (int j = 0; j < 4; ++j)
                acc[i][j] = __builtin_amdgcn_mfma_f32_16x16x32_bf16(af[i], bfr[j], acc[i][j], 0, 0, 0);
        __syncthreads();
    }

    // ah = C + bo + ffn (fp32 in regs); per-row partial sums
    #pragma unroll
    for (int i = 0; i < 4; ++i) {
        #pragma unroll
        for (int r = 0; r < 4; ++r) {
            const int rl = wr * 64 + i * 16 + quad * 4 + r;
            const int grow = row0 + rl;
            float s = 0.f, q = 0.f;
            #pragma unroll
            for (int j = 0; j < 4; ++j) {
                const int col = wc * 64 + j * 16 + m16;
                float v = acc[i][j][r] + bo[col];
                if (grow < M) v += bflo(ffnb[(size_t)grow * 128 + col]);
                acc[i][j][r] = v;
                s += v; q += v * v;
            }
            #pragma unroll
            for (int mm = 1; mm <= 8; mm <<= 1) {
                s += __shfl_xor(s, mm, 16);
                q += __shfl_xor(q, mm, 16);
            }
            if (m16 == 0) { rsum[wc][rl] = s; rsq[wc][rl] = q; }
        }
    }
    __syncthreads();
    if (tid < 128) {
        const float s = rsum[0][tid] + rsum[1][tid];
        const float q = rsq[0][tid] + rsq[1][tid];
        const float mean = s * (1.f / 128.f);
        const float var  = q * (1.f / 128.f) - mean * mean;
        meanar[tid] = mean;
        invar[tid]  = rsqrtf(fmaxf(var, 0.f) + 1e-5f);
    }
    __syncthreads();

    #pragma unroll
    for (int i = 0; i < 4; ++i) {
        #pragma unroll
        for (int j = 0; j < 4; ++j) {
            const int col = wc * 64 + j * 16 + m16;
            const float gv = g[col], lv = bln[col];
            #pragma unroll
            for (int r = 0; r < 4; ++r) {
                const int rl = wr * 64 + i * 16 + quad * 4 + r;
                const int grow = row0 + rl;
                if (grow < M) {
                    const float v = acc[i][j][r];
                    Y[(size_t)grow * 128 + col] = v + (v - meanar[rl]) * invar[rl] * gv + lv;
                }
            }
        }
    }
}

// ---------------------------------------------------------------------------
extern "C" void kernel_launch(void* const* d_in, const int* in_sizes, int n_in,
                              void* d_out, int out_size, void* d_ws, size_t ws_size,
                              hipStream_t stream) {
    const float* x99   = (const float*)d_in[2];
    const float* feat0 = (const float*)d_in[3];
    const float* feat1 = (const float*)d_in[4];
    const float* Waq   = (const float*)d_in[10];
    const float* Wak   = (const float*)d_in[11];
    const float* Wav   = (const float*)d_in[12];
    const float* Wao   = (const float*)d_in[13];
    const float* Waffn = (const float*)d_in[14];
    const float* baq   = (const float*)d_in[20];
    const float* bak   = (const float*)d_in[21];
    const float* bav   = (const float*)d_in[22];
    const float* bao   = (const float*)d_in[23];
    const float* baffn = (const float*)d_in[24];
    const float* aln_b = (const float*)d_in[26];
    const float* aln_g = (const float*)d_in[28];
    const int* src0 = (const int*)d_in[29];
    const int* dst0 = (const int*)d_in[30];
    const int* src1 = (const int*)d_in[31];
    const int* dst1 = (const int*)d_in[32];

    // workspace (~90 MB)
    unsigned short* xb   = (unsigned short*)d_ws;                 // NN*256 us
    unsigned short* qb   = xb + (size_t)NN * 256;                 // NN*128 us
    unsigned char*  kv8  = (unsigned char*)(qb + (size_t)NN * 128);   // NN*256 bytes
    unsigned short* ffnb = (unsigned short*)(kv8 + (size_t)NN * 256); // NN*128 us
    unsigned short* att  = ffnb + (size_t)NN * 128;               // 2*NN*128 us
    unsigned short* Wt   = att  + (size_t)NTOT * 128;             // 512*256 us
    unsigned short* Waot = Wt   + (size_t)512 * 256;              // 128*128 us
    int* cursor = (int*)(Waot + 128 * 128);                       // NB
    int* off    = cursor + NB;                                    // NTOT
    int* deg    = off + NTOT;                                     // NTOT

    float* out = (float*)d_out;
    // stage_rec (8.0 MB) + stage_loc (2.0 MB) + erec (6.4 MB) parked in
    // d_out; all fully consumed (fuse2, aggregate) before attn_out writes.
    unsigned int*  stage_rec = (unsigned int*)d_out;              // NB*CAP u32
    unsigned char* stage_loc = (unsigned char*)(stage_rec + (size_t)NB * CAP); // NB*CAP u8
    unsigned int*  erec = (unsigned int*)(stage_loc + (size_t)NB * CAP);       // 2*EE u32

    hipMemsetAsync(cursor, 0, NB * sizeof(int), stream);

    fuse1_k<<<F1_CVTX + F1_CVTW + F1_BIN, 256, 0, stream>>>(
        x99, xb, Waq, Wak, Wav, Waffn, Wao, Wt, Waot,
        dst0, dst1, src0, src1, feat0, feat1, cursor, stage_rec, stage_loc);

    fuse2_k<<<F2_QKVF + NB, 256, 0, stream>>>(
        xb, Wt, baq, bak, bav, baffn, qb, kv8, ffnb, NN,
        stage_rec, stage_loc, cursor, erec, off, deg);

    aggregate_k<<<(NTOT + 3) / 4, 256, 0, stream>>>(qb, kv8, erec, off, deg, att);
    attn_out_mfma_k<<<8 * RPX * 2, 256, 0, stream>>>(att, Waot, bao, ffnb, aln_g, aln_b, out, NN);
}